// Round 1
// baseline (834.421 us; speedup 1.0000x reference)
//
#include <hip/hip_runtime.h>
#include <math.h>

#define SLOPE 0.2f

static __device__ __forceinline__ float leakyf(float x) { return x >= 0.f ? x : SLOPE * x; }

// ---------------- GEMM: C[M,Nc] = A[M,K] @ B[K,Nc] (row-major), optional accumulate ----
// BM=64, BN=64, BK=16, 256 threads, 4x4 per thread.
template<bool ACC>
__global__ __launch_bounds__(256) void gemm_f32(const float* __restrict__ A,
                                                const float* __restrict__ B,
                                                float* __restrict__ C,
                                                int M, int K, int Nc) {
    __shared__ float As[16][65];
    __shared__ float Bs[16][65];
    const int tid = threadIdx.x;
    const int bm = blockIdx.y * 64;
    const int bn = blockIdx.x * 64;
    const int tr = tid >> 4;   // 0..15
    const int tc = tid & 15;   // 0..15

    float acc[4][4] = {};

    for (int k0 = 0; k0 < K; k0 += 16) {
        // A tile: 64 rows x 16 cols; each thread one float4
        {
            int ar = tid >> 2;          // 0..63
            int ac = (tid & 3) * 4;     // 0,4,8,12
            float4 av = make_float4(0.f, 0.f, 0.f, 0.f);
            if (bm + ar < M)
                av = *(const float4*)(A + (size_t)(bm + ar) * K + k0 + ac);
            As[ac + 0][ar] = av.x;
            As[ac + 1][ar] = av.y;
            As[ac + 2][ar] = av.z;
            As[ac + 3][ar] = av.w;
        }
        // B tile: 16 rows x 64 cols; each thread one float4
        {
            int br = tid >> 4;          // 0..15
            int bc = (tid & 15) * 4;    // 0..60
            float4 bv = *(const float4*)(B + (size_t)(k0 + br) * Nc + bn + bc);
            Bs[br][bc + 0] = bv.x;
            Bs[br][bc + 1] = bv.y;
            Bs[br][bc + 2] = bv.z;
            Bs[br][bc + 3] = bv.w;
        }
        __syncthreads();
#pragma unroll
        for (int kk = 0; kk < 16; ++kk) {
            float a0[4], b0[4];
#pragma unroll
            for (int i = 0; i < 4; ++i) a0[i] = As[kk][tr * 4 + i];
#pragma unroll
            for (int j = 0; j < 4; ++j) b0[j] = Bs[kk][tc * 4 + j];
#pragma unroll
            for (int i = 0; i < 4; ++i)
#pragma unroll
                for (int j = 0; j < 4; ++j) acc[i][j] += a0[i] * b0[j];
        }
        __syncthreads();
    }

#pragma unroll
    for (int i = 0; i < 4; ++i) {
        int r = bm + tr * 4 + i;
        if (r >= M) continue;
#pragma unroll
        for (int j = 0; j < 4; ++j) {
            int c = bn + tc * 4 + j;
            float v = acc[i][j];
            if (ACC) v += C[(size_t)r * Nc + c];
            C[(size_t)r * Nc + c] = v;
        }
    }
}

// ---------------- attention projections: el[n,h]=sum_f feat[n,h,f]*al[h,f] -------------
template<int H>
__global__ __launch_bounds__(256) void attn_proj(const float* __restrict__ feat,
                                                 const float* __restrict__ al,
                                                 const float* __restrict__ ar,
                                                 float* __restrict__ el,
                                                 float* __restrict__ er, int n) {
    int wave = blockIdx.x * 4 + (threadIdx.x >> 6);
    int lane = threadIdx.x & 63;
    if (wave >= n) return;
    const float* f = feat + (size_t)wave * (H * 64);
    float pl[H], pr[H];
#pragma unroll
    for (int h = 0; h < H; ++h) {
        float v = f[h * 64 + lane];
        pl[h] = v * al[h * 64 + lane];
        pr[h] = v * ar[h * 64 + lane];
    }
#pragma unroll
    for (int off = 32; off > 0; off >>= 1) {
#pragma unroll
        for (int h = 0; h < H; ++h) {
            pl[h] += __shfl_xor(pl[h], off);
            pr[h] += __shfl_xor(pr[h], off);
        }
    }
    if (lane == 0) {
#pragma unroll
        for (int h = 0; h < H; ++h) {
            el[(size_t)wave * H + h] = pl[h];
            er[(size_t)wave * H + h] = pr[h];
        }
    }
}

// ---------------- CSR build ------------------------------------------------------------
__global__ void hist_kernel(const int* __restrict__ dst, int* __restrict__ counts, int e) {
    int i = blockIdx.x * blockDim.x + threadIdx.x;
    if (i < e) atomicAdd(&counts[dst[i]], 1);
}

__global__ void scan_kernel(const int* __restrict__ counts, int* __restrict__ offsets, int n) {
    __shared__ int sm[1024];
    __shared__ int carry_s;
    int tid = threadIdx.x;
    if (tid == 0) carry_s = 0;
    __syncthreads();
    for (int base = 0; base < n; base += 1024) {
        int idx = base + tid;
        int v = (idx < n) ? counts[idx] : 0;
        sm[tid] = v;
        __syncthreads();
        for (int off = 1; off < 1024; off <<= 1) {
            int t = (tid >= off) ? sm[tid - off] : 0;
            __syncthreads();
            sm[tid] += t;
            __syncthreads();
        }
        int inc = sm[tid];
        if (idx < n) offsets[idx] = carry_s + inc - v;
        __syncthreads();
        if (tid == 1023) carry_s += sm[1023];
        __syncthreads();
    }
    if (tid == 0) offsets[n] = carry_s;
}

__global__ void copy_int_kernel(const int* __restrict__ a, int* __restrict__ b, int n) {
    int i = blockIdx.x * blockDim.x + threadIdx.x;
    if (i < n) b[i] = a[i];
}

__global__ void scatter_kernel(const int* __restrict__ src, const int* __restrict__ dst,
                               int* __restrict__ cursor, int* __restrict__ csr_src, int e) {
    int i = blockIdx.x * blockDim.x + threadIdx.x;
    if (i < e) {
        int pos = atomicAdd(&cursor[dst[i]], 1);
        csr_src[pos] = src[i];
    }
}

// ---------------- per-node edge softmax + aggregate ------------------------------------
// one wave per destination node; lane covers feature f (=lane) of every head.
// ACT: 0 = none, 1 = elu.  RES: add resid before activation.
template<int H, bool RES, int ACT>
__global__ __launch_bounds__(256) void gat_agg(const float* __restrict__ feat,
                                               const float* __restrict__ el,
                                               const float* __restrict__ er,
                                               const int* __restrict__ offsets,
                                               const int* __restrict__ csr_src,
                                               const float* __restrict__ resid,
                                               float* __restrict__ out, int n) {
    int node = blockIdx.x * 4 + (threadIdx.x >> 6);
    int lane = threadIdx.x & 63;
    if (node >= n) return;

    int e0 = offsets[node];
    int e1 = offsets[node + 1];

    float erh[H];
#pragma unroll
    for (int h = 0; h < H; ++h) erh[h] = er[(size_t)node * H + h];

    float m[H];
#pragma unroll
    for (int h = 0; h < H; ++h) m[h] = -INFINITY;

    for (int e = e0; e < e1; ++e) {
        int s = csr_src[e];
#pragma unroll
        for (int h = 0; h < H; ++h) {
            float x = leakyf(el[(size_t)s * H + h] + erh[h]);
            m[h] = fmaxf(m[h], x);
        }
    }

    float acc[H], den[H];
#pragma unroll
    for (int h = 0; h < H; ++h) { acc[h] = 0.f; den[h] = 0.f; }

    for (int e = e0; e < e1; ++e) {
        int s = csr_src[e];
        const float* fs = feat + (size_t)s * (H * 64);
#pragma unroll
        for (int h = 0; h < H; ++h) {
            float x = leakyf(el[(size_t)s * H + h] + erh[h]);
            float w = __expf(x - m[h]);
            den[h] += w;
            acc[h] += fs[h * 64 + lane] * w;
        }
    }

#pragma unroll
    for (int h = 0; h < H; ++h) {
        float v = (den[h] > 0.f) ? acc[h] / den[h] : 0.f;
        if (RES) v += resid[(size_t)node * (H * 64) + h * 64 + lane];
        if (ACT == 1) v = (v > 0.f) ? v : (__expf(v) - 1.f);
        out[(size_t)node * (H * 64) + h * 64 + lane] = v;
    }
}

// ---------------- launcher --------------------------------------------------------------
extern "C" void kernel_launch(void* const* d_in, const int* in_sizes, int n_in,
                              void* d_out, int out_size, void* d_ws, size_t ws_size,
                              hipStream_t stream) {
    const float* x      = (const float*)d_in[0];
    const float* W1     = (const float*)d_in[1];
    const float* al1    = (const float*)d_in[2];
    const float* ar1    = (const float*)d_in[3];
    const float* W2     = (const float*)d_in[4];
    const float* al2    = (const float*)d_in[5];
    const float* ar2    = (const float*)d_in[6];
    const float* W3     = (const float*)d_in[7];
    const float* al3    = (const float*)d_in[8];
    const float* ar3    = (const float*)d_in[9];
    const float* res_W3 = (const float*)d_in[10];
    const int*   src    = (const int*)d_in[11];
    const int*   dst    = (const int*)d_in[12];

    const int N = in_sizes[0] / 128;    // 50000
    const int E = in_sizes[11];         // 500000
    const int D = 256;                  // 4 heads * 64

    float* out = (float*)d_out;

    // workspace layout
    float* A  = (float*)d_ws;          // [N,256] layer outputs (h)
    float* Bf = A + (size_t)N * D;     // [N,256] GEMM feat
    float* C  = Bf + (size_t)N * D;    // [N,256]
    float* el = C + (size_t)N * D;     // [N,4]
    float* er = el + (size_t)N * 4;    // [N,4]
    int* offsets = (int*)(er + (size_t)N * 4);  // [N+1]
    int* cursor  = offsets + (N + 1);           // [N]
    int* csr_src = cursor + N;                  // [E]

    const int T = 256;

    // ---- CSR by dst (same for all layers) ----
    hipMemsetAsync(cursor, 0, (size_t)N * sizeof(int), stream);
    hist_kernel<<<(E + T - 1) / T, T, 0, stream>>>(dst, cursor, E);
    scan_kernel<<<1, 1024, 0, stream>>>(cursor, offsets, N);
    copy_int_kernel<<<(N + T - 1) / T, T, 0, stream>>>(offsets, cursor, N);
    scatter_kernel<<<(E + T - 1) / T, T, 0, stream>>>(src, dst, cursor, csr_src, E);

    dim3 gemm_grid_256(256 / 64, (N + 63) / 64);
    dim3 gemm_grid_64(64 / 64, (N + 63) / 64);
    int node_blocks = (N + 3) / 4;

    // ---- Layer 1: x[ N,128 ] @ W1 -> feat; agg -> A; elu ----
    gemm_f32<false><<<gemm_grid_256, T, 0, stream>>>(x, W1, Bf, N, 128, 256);
    attn_proj<4><<<node_blocks, T, 0, stream>>>(Bf, al1, ar1, el, er, N);
    gat_agg<4, false, 1><<<node_blocks, T, 0, stream>>>(Bf, el, er, offsets, csr_src, nullptr, A, N);

    // ---- Layer 2: A @ W2 -> feat; agg + residual(A) -> C; elu ----
    gemm_f32<false><<<gemm_grid_256, T, 0, stream>>>(A, W2, Bf, N, 256, 256);
    attn_proj<4><<<node_blocks, T, 0, stream>>>(Bf, al2, ar2, el, er, N);
    gat_agg<4, true, 1><<<node_blocks, T, 0, stream>>>(Bf, el, er, offsets, csr_src, A, C, N);

    // ---- Layer 3: C @ W3 -> feat (N,64); agg -> out; out += C @ res_W3 ----
    gemm_f32<false><<<gemm_grid_64, T, 0, stream>>>(C, W3, Bf, N, 256, 64);
    attn_proj<1><<<node_blocks, T, 0, stream>>>(Bf, al3, ar3, el, er, N);
    gat_agg<1, false, 0><<<node_blocks, T, 0, stream>>>(Bf, el, er, offsets, csr_src, nullptr, out, N);
    gemm_f32<true><<<gemm_grid_64, T, 0, stream>>>(C, res_W3, out, N, 256, 64);
}

// Round 2
// 600.897 us; speedup vs baseline: 1.3886x; 1.3886x over previous
//
#include <hip/hip_runtime.h>
#include <hip/hip_bf16.h>
#include <math.h>

#define SLOPE 0.2f

typedef __attribute__((ext_vector_type(8))) short short8;
typedef __attribute__((ext_vector_type(4))) float f32x4;

static __device__ __forceinline__ float leakyf(float x) { return x >= 0.f ? x : SLOPE * x; }

// ---------------- conversions ------------------------------------------------------------
__global__ void cvt_bf16(const float* __restrict__ in, __hip_bfloat16* __restrict__ o, int n) {
    int i = (blockIdx.x * blockDim.x + threadIdx.x) * 4;
    if (i + 3 < n) {
        float4 v = *(const float4*)(in + i);
        o[i + 0] = __float2bfloat16(v.x);
        o[i + 1] = __float2bfloat16(v.y);
        o[i + 2] = __float2bfloat16(v.z);
        o[i + 3] = __float2bfloat16(v.w);
    } else {
        for (int j = i; j < n; ++j) o[j] = __float2bfloat16(in[j]);
    }
}

// Wt[n][k] = W[k][n], bf16
__global__ void tconv(const float* __restrict__ W, __hip_bfloat16* __restrict__ Wt, int K, int Nc) {
    int i = blockIdx.x * blockDim.x + threadIdx.x;
    if (i < K * Nc) {
        int k = i / Nc, n = i - k * Nc;
        Wt[(size_t)n * K + k] = __float2bfloat16(W[i]);
    }
}

// ---------------- MFMA GEMM: out[M,Nc] = A[M,K](bf16) @ Wt[Nc,K](bf16)^T ----------------
// block = 4 waves = 64 rows; wave w covers cols [w*NF_N*16, (w+1)*NF_N*16); Nc = NF_N*64.
template<int NF_N, bool ACC, bool OUT_BF16>
__global__ __launch_bounds__(256) void gemm_bf16(const __hip_bfloat16* __restrict__ A,
                                                 const __hip_bfloat16* __restrict__ Wt,
                                                 void* __restrict__ outv,
                                                 int M, int K) {
    const int Nc = NF_N * 64;
    const int lane = threadIdx.x & 63;
    const int wid = threadIdx.x >> 6;
    const int m0 = blockIdx.x * 64;
    const int rlo = lane & 15;
    const int kg = (lane >> 4) * 8;

    f32x4 acc[4][NF_N];
#pragma unroll
    for (int mf = 0; mf < 4; ++mf)
#pragma unroll
        for (int nf = 0; nf < NF_N; ++nf) acc[mf][nf] = (f32x4){0.f, 0.f, 0.f, 0.f};

    for (int k0 = 0; k0 < K; k0 += 32) {
        short8 a[4];
#pragma unroll
        for (int mf = 0; mf < 4; ++mf) {
            int r = m0 + mf * 16 + rlo;
            if (r >= M) r = M - 1;  // duplicate row; only affects unstored output rows
            a[mf] = *(const short8*)(A + (size_t)r * K + k0 + kg);
        }
#pragma unroll
        for (int nf = 0; nf < NF_N; ++nf) {
            int c = (wid * NF_N + nf) * 16 + rlo;
            short8 b = *(const short8*)(Wt + (size_t)c * K + k0 + kg);
#pragma unroll
            for (int mf = 0; mf < 4; ++mf)
                acc[mf][nf] = __builtin_amdgcn_mfma_f32_16x16x32_bf16(a[mf], b, acc[mf][nf], 0, 0, 0);
        }
    }

#pragma unroll
    for (int mf = 0; mf < 4; ++mf) {
#pragma unroll
        for (int nf = 0; nf < NF_N; ++nf) {
            int c = (wid * NF_N + nf) * 16 + rlo;
#pragma unroll
            for (int reg = 0; reg < 4; ++reg) {
                int r = m0 + mf * 16 + (lane >> 4) * 4 + reg;
                if (r >= M) continue;
                float v = acc[mf][nf][reg];
                if (OUT_BF16) {
                    ((__hip_bfloat16*)outv)[(size_t)r * Nc + c] = __float2bfloat16(v);
                } else {
                    float* o = (float*)outv + (size_t)r * Nc + c;
                    *o = ACC ? (*o + v) : v;
                }
            }
        }
    }
}

// ---------------- attention projections --------------------------------------------------
template<int H>
__global__ __launch_bounds__(256) void attn_proj(const __hip_bfloat16* __restrict__ feat,
                                                 const float* __restrict__ al,
                                                 const float* __restrict__ ar,
                                                 float* __restrict__ el,
                                                 float* __restrict__ er, int n) {
    int node = blockIdx.x * 4 + (threadIdx.x >> 6);
    int lane = threadIdx.x & 63;
    if (node >= n) return;
    const __hip_bfloat16* f = feat + (size_t)node * (H * 64);
    float pl[H], pr[H];
#pragma unroll
    for (int h = 0; h < H; ++h) {
        float v = __bfloat162float(f[h * 64 + lane]);
        pl[h] = v * al[h * 64 + lane];
        pr[h] = v * ar[h * 64 + lane];
    }
#pragma unroll
    for (int off = 32; off > 0; off >>= 1) {
#pragma unroll
        for (int h = 0; h < H; ++h) {
            pl[h] += __shfl_xor(pl[h], off);
            pr[h] += __shfl_xor(pr[h], off);
        }
    }
    if (lane == 0) {
#pragma unroll
        for (int h = 0; h < H; ++h) {
            el[(size_t)node * H + h] = pl[h];
            er[(size_t)node * H + h] = pr[h];
        }
    }
}

// ---------------- CSR build --------------------------------------------------------------
__global__ void hist_kernel(const int* __restrict__ dst, int* __restrict__ counts, int e) {
    int i = blockIdx.x * blockDim.x + threadIdx.x;
    if (i < e) atomicAdd(&counts[dst[i]], 1);
}

__global__ __launch_bounds__(1024) void scan_kernel(const int* __restrict__ counts,
                                                    int* __restrict__ offsets, int n) {
    __shared__ int wsums[16];
    __shared__ int carry_s;
    int tid = threadIdx.x, lane = tid & 63, wid = tid >> 6;
    if (tid == 0) carry_s = 0;
    __syncthreads();
    for (int base = 0; base < n; base += 1024) {
        int idx = base + tid;
        int v = (idx < n) ? counts[idx] : 0;
        int s = v;
#pragma unroll
        for (int off = 1; off < 64; off <<= 1) {
            int t = __shfl_up(s, off);
            if (lane >= off) s += t;
        }
        if (lane == 63) wsums[wid] = s;
        __syncthreads();
        if (wid == 0 && lane < 16) {
            int ws = wsums[lane];
#pragma unroll
            for (int off = 1; off < 16; off <<= 1) {
                int t = __shfl_up(ws, off);
                if (lane >= off) ws += t;
            }
            wsums[lane] = ws;
        }
        __syncthreads();
        int wprefix = (wid > 0) ? wsums[wid - 1] : 0;
        int total = wsums[15];
        if (idx < n) offsets[idx] = carry_s + wprefix + s - v;
        __syncthreads();
        if (tid == 0) carry_s += total;
        __syncthreads();
    }
    if (tid == 0) offsets[n] = carry_s;
}

__global__ void copy_int_kernel(const int* __restrict__ a, int* __restrict__ b, int n) {
    int i = blockIdx.x * blockDim.x + threadIdx.x;
    if (i < n) b[i] = a[i];
}

__global__ void scatter_kernel(const int* __restrict__ src, const int* __restrict__ dst,
                               int* __restrict__ cursor, int* __restrict__ csr_src, int e) {
    int i = blockIdx.x * blockDim.x + threadIdx.x;
    if (i < e) {
        int pos = atomicAdd(&cursor[dst[i]], 1);
        csr_src[pos] = src[i];
    }
}

// ---------------- per-node edge softmax + aggregate --------------------------------------
template<int H, bool RES, int ACT, bool OUT_BF16>
__global__ __launch_bounds__(256) void gat_agg(const __hip_bfloat16* __restrict__ feat,
                                               const float* __restrict__ el,
                                               const float* __restrict__ er,
                                               const int* __restrict__ offsets,
                                               const int* __restrict__ csr_src,
                                               const __hip_bfloat16* __restrict__ resid,
                                               void* __restrict__ outv, int n) {
    int node = blockIdx.x * 4 + (threadIdx.x >> 6);
    int lane = threadIdx.x & 63;
    if (node >= n) return;

    int e0 = offsets[node];
    int e1 = offsets[node + 1];

    float erh[H];
#pragma unroll
    for (int h = 0; h < H; ++h) erh[h] = er[(size_t)node * H + h];

    float m[H];
#pragma unroll
    for (int h = 0; h < H; ++h) m[h] = -INFINITY;

    for (int e = e0; e < e1; ++e) {
        int s = csr_src[e];
#pragma unroll
        for (int h = 0; h < H; ++h) {
            float x = leakyf(el[(size_t)s * H + h] + erh[h]);
            m[h] = fmaxf(m[h], x);
        }
    }

    float acc[H], den[H];
#pragma unroll
    for (int h = 0; h < H; ++h) { acc[h] = 0.f; den[h] = 0.f; }

    for (int e = e0; e < e1; ++e) {
        int s = csr_src[e];
        const __hip_bfloat16* fs = feat + (size_t)s * (H * 64);
#pragma unroll
        for (int h = 0; h < H; ++h) {
            float x = leakyf(el[(size_t)s * H + h] + erh[h]);
            float w = __expf(x - m[h]);
            den[h] += w;
            acc[h] += __bfloat162float(fs[h * 64 + lane]) * w;
        }
    }

#pragma unroll
    for (int h = 0; h < H; ++h) {
        float v = (den[h] > 0.f) ? acc[h] / den[h] : 0.f;
        if (RES) v += __bfloat162float(resid[(size_t)node * (H * 64) + h * 64 + lane]);
        if (ACT == 1) v = (v > 0.f) ? v : (__expf(v) - 1.f);
        size_t oi = (size_t)node * (H * 64) + h * 64 + lane;
        if (OUT_BF16) ((__hip_bfloat16*)outv)[oi] = __float2bfloat16(v);
        else ((float*)outv)[oi] = v;
    }
}

// ---------------- launcher ----------------------------------------------------------------
extern "C" void kernel_launch(void* const* d_in, const int* in_sizes, int n_in,
                              void* d_out, int out_size, void* d_ws, size_t ws_size,
                              hipStream_t stream) {
    const float* x      = (const float*)d_in[0];
    const float* W1     = (const float*)d_in[1];
    const float* al1    = (const float*)d_in[2];
    const float* ar1    = (const float*)d_in[3];
    const float* W2     = (const float*)d_in[4];
    const float* al2    = (const float*)d_in[5];
    const float* ar2    = (const float*)d_in[6];
    const float* W3     = (const float*)d_in[7];
    const float* al3    = (const float*)d_in[8];
    const float* ar3    = (const float*)d_in[9];
    const float* res_W3 = (const float*)d_in[10];
    const int*   src    = (const int*)d_in[11];
    const int*   dst    = (const int*)d_in[12];

    const int N = in_sizes[0] / 128;    // 50000
    const int E = in_sizes[11];         // 500000

    float* out = (float*)d_out;

    // workspace layout (bf16 = 2B)
    __hip_bfloat16* xb    = (__hip_bfloat16*)d_ws;          // [N,128]
    __hip_bfloat16* featb = xb + (size_t)N * 128;           // [N,256] (layer3 reuses as [N,64])
    __hip_bfloat16* h1    = featb + (size_t)N * 256;        // [N,256]
    __hip_bfloat16* h2    = h1 + (size_t)N * 256;           // [N,256]
    __hip_bfloat16* W1t   = h2 + (size_t)N * 256;           // [256,128]
    __hip_bfloat16* W2t   = W1t + 128 * 256;                // [256,256]
    __hip_bfloat16* W3t   = W2t + 256 * 256;                // [64,256]
    __hip_bfloat16* RW3t  = W3t + 256 * 64;                 // [64,256]
    float* el = (float*)(RW3t + 256 * 64);                  // [N,4]
    float* er = el + (size_t)N * 4;                         // [N,4]
    int* offsets = (int*)(er + (size_t)N * 4);              // [N+1]
    int* cursor  = offsets + (N + 1);                       // [N]
    int* csr_src = cursor + N;                              // [E]

    const int T = 256;

    // ---- conversions ----
    cvt_bf16<<<(N * 128 / 4 + T - 1) / T, T, 0, stream>>>(x, xb, N * 128);
    tconv<<<(128 * 256 + T - 1) / T, T, 0, stream>>>(W1, W1t, 128, 256);
    tconv<<<(256 * 256 + T - 1) / T, T, 0, stream>>>(W2, W2t, 256, 256);
    tconv<<<(256 * 64 + T - 1) / T, T, 0, stream>>>(W3, W3t, 256, 64);
    tconv<<<(256 * 64 + T - 1) / T, T, 0, stream>>>(res_W3, RW3t, 256, 64);

    // ---- CSR by dst (same for all layers) ----
    hipMemsetAsync(cursor, 0, (size_t)N * sizeof(int), stream);
    hist_kernel<<<(E + T - 1) / T, T, 0, stream>>>(dst, cursor, E);
    scan_kernel<<<1, 1024, 0, stream>>>(cursor, offsets, N);
    copy_int_kernel<<<(N + T - 1) / T, T, 0, stream>>>(offsets, cursor, N);
    scatter_kernel<<<(E + T - 1) / T, T, 0, stream>>>(src, dst, cursor, csr_src, E);

    int gemm_blocks = (N + 63) / 64;
    int node_blocks = (N + 3) / 4;

    // ---- Layer 1: feat = xb @ W1 ; agg -> h1 (elu, bf16) ----
    gemm_bf16<4, false, true><<<gemm_blocks, T, 0, stream>>>(xb, W1t, featb, N, 128);
    attn_proj<4><<<node_blocks, T, 0, stream>>>(featb, al1, ar1, el, er, N);
    gat_agg<4, false, 1, true><<<node_blocks, T, 0, stream>>>(featb, el, er, offsets, csr_src, nullptr, h1, N);

    // ---- Layer 2: feat = h1 @ W2 ; agg + resid(h1) -> h2 (elu, bf16) ----
    gemm_bf16<4, false, true><<<gemm_blocks, T, 0, stream>>>(h1, W2t, featb, N, 256);
    attn_proj<4><<<node_blocks, T, 0, stream>>>(featb, al2, ar2, el, er, N);
    gat_agg<4, true, 1, true><<<node_blocks, T, 0, stream>>>(featb, el, er, offsets, csr_src, h1, h2, N);

    // ---- Layer 3: feat = h2 @ W3 (N,64) ; agg -> out (f32) ; out += h2 @ res_W3 ----
    gemm_bf16<1, false, true><<<gemm_blocks, T, 0, stream>>>(h2, W3t, featb, N, 256);
    attn_proj<1><<<node_blocks, T, 0, stream>>>(featb, al3, ar3, el, er, N);
    gat_agg<1, false, 0, false><<<node_blocks, T, 0, stream>>>(featb, el, er, offsets, csr_src, nullptr, out, N);
    gemm_bf16<1, true, false><<<gemm_blocks, T, 0, stream>>>(h2, RW3t, out, N, 256);
}

// Round 3
// 312.406 us; speedup vs baseline: 2.6710x; 1.9234x over previous
//
#include <hip/hip_runtime.h>
#include <hip/hip_bf16.h>
#include <math.h>

#define SLOPE 0.2f

typedef __attribute__((ext_vector_type(8))) short short8;
typedef __attribute__((ext_vector_type(4))) float f32x4;

static __device__ __forceinline__ float leakyf(float x) { return x >= 0.f ? x : SLOPE * x; }
static __device__ __forceinline__ float bflo(unsigned u) { return __builtin_bit_cast(float, u << 16); }
static __device__ __forceinline__ float bfhi(unsigned u) { return __builtin_bit_cast(float, u & 0xffff0000u); }

struct __align__(8) bf16x4 { __hip_bfloat16 x, y, z, w; };

// ---------------- conversions ------------------------------------------------------------
__global__ void cvt_bf16(const float* __restrict__ in, __hip_bfloat16* __restrict__ o, int n) {
    int i = (blockIdx.x * blockDim.x + threadIdx.x) * 4;
    if (i + 3 < n) {
        float4 v = *(const float4*)(in + i);
        o[i + 0] = __float2bfloat16(v.x);
        o[i + 1] = __float2bfloat16(v.y);
        o[i + 2] = __float2bfloat16(v.z);
        o[i + 3] = __float2bfloat16(v.w);
    } else {
        for (int j = i; j < n; ++j) o[j] = __float2bfloat16(in[j]);
    }
}

// Wt[n][k] = W[k][n], bf16
__global__ void tconv(const float* __restrict__ W, __hip_bfloat16* __restrict__ Wt, int K, int Nc) {
    int i = blockIdx.x * blockDim.x + threadIdx.x;
    if (i < K * Nc) {
        int k = i / Nc, n = i - k * Nc;
        Wt[(size_t)n * K + k] = __float2bfloat16(W[i]);
    }
}

// ---------------- MFMA GEMM + fused attention projections --------------------------------
// HEADS==4: Nc=256, block covers 64 rows, wave w = col stripe [w*64, w*64+64) = head w.
// HEADS==1: Nc=64,  block covers 256 rows, wave w = rows [blk*256+w*64, +64), all 64 cols.
// DO_ATTN: el[r,head] = sum_c feat[r,c]*al[head,c] reduced from accumulators in-register.
template<int HEADS, bool ACC, bool OUT_BF16, bool DO_ATTN>
__global__ __launch_bounds__(256) void gemm_bf16(const __hip_bfloat16* __restrict__ A,
                                                 const __hip_bfloat16* __restrict__ Wt,
                                                 void* __restrict__ outv,
                                                 const float* __restrict__ al,
                                                 const float* __restrict__ ar,
                                                 float* __restrict__ el,
                                                 float* __restrict__ er,
                                                 int M, int K) {
    const int Nc = HEADS * 64;
    const int lane = threadIdx.x & 63;
    const int wid = threadIdx.x >> 6;
    const int rlo = lane & 15;
    const int q = lane >> 4;
    const int kg = q * 8;
    const int head = (HEADS == 4) ? wid : 0;
    const int m0 = (HEADS == 4) ? blockIdx.x * 64 : blockIdx.x * 256 + wid * 64;
    const int cbase = head * 64;

    f32x4 acc[4][4];
#pragma unroll
    for (int mf = 0; mf < 4; ++mf)
#pragma unroll
        for (int nf = 0; nf < 4; ++nf) acc[mf][nf] = (f32x4){0.f, 0.f, 0.f, 0.f};

    for (int k0 = 0; k0 < K; k0 += 32) {
        short8 a[4];
#pragma unroll
        for (int mf = 0; mf < 4; ++mf) {
            int r = m0 + mf * 16 + rlo;
            if (r >= M) r = M - 1;  // duplicate row; affects only unstored rows
            a[mf] = *(const short8*)(A + (size_t)r * K + k0 + kg);
        }
#pragma unroll
        for (int nf = 0; nf < 4; ++nf) {
            short8 b = *(const short8*)(Wt + (size_t)(cbase + nf * 16 + rlo) * K + k0 + kg);
#pragma unroll
            for (int mf = 0; mf < 4; ++mf)
                acc[mf][nf] = __builtin_amdgcn_mfma_f32_16x16x32_bf16(a[mf], b, acc[mf][nf], 0, 0, 0);
        }
    }

    float alv[4], arv[4];
    if (DO_ATTN) {
#pragma unroll
        for (int nf = 0; nf < 4; ++nf) {
            alv[nf] = al[cbase + nf * 16 + rlo];
            arv[nf] = ar[cbase + nf * 16 + rlo];
        }
    }

#pragma unroll
    for (int mf = 0; mf < 4; ++mf) {
#pragma unroll
        for (int reg = 0; reg < 4; ++reg) {
            int r = m0 + mf * 16 + q * 4 + reg;
            if (DO_ATTN) {
                float pl = 0.f, pr = 0.f;
#pragma unroll
                for (int nf = 0; nf < 4; ++nf) {
                    pl += acc[mf][nf][reg] * alv[nf];
                    pr += acc[mf][nf][reg] * arv[nf];
                }
#pragma unroll
                for (int off = 1; off < 16; off <<= 1) {
                    pl += __shfl_xor(pl, off);
                    pr += __shfl_xor(pr, off);
                }
                if (rlo == 0 && r < M) {
                    el[(size_t)r * HEADS + head] = pl;
                    er[(size_t)r * HEADS + head] = pr;
                }
            }
            if (r < M) {
#pragma unroll
                for (int nf = 0; nf < 4; ++nf) {
                    int c = cbase + nf * 16 + rlo;
                    float v = acc[mf][nf][reg];
                    if (OUT_BF16) {
                        ((__hip_bfloat16*)outv)[(size_t)r * Nc + c] = __float2bfloat16(v);
                    } else {
                        float* o = (float*)outv + (size_t)r * Nc + c;
                        *o = ACC ? (*o + v) : v;
                    }
                }
            }
        }
    }
}

// ---------------- CSR build --------------------------------------------------------------
__global__ void hist_kernel(const int* __restrict__ dst, int* __restrict__ counts, int e) {
    int i = blockIdx.x * blockDim.x + threadIdx.x;
    if (i < e) atomicAdd(&counts[dst[i]], 1);
}

__global__ __launch_bounds__(1024) void scan_block(const int* __restrict__ counts,
                                                   int* __restrict__ offsets,
                                                   int* __restrict__ bsums, int n) {
    __shared__ int ws[16];
    int tid = threadIdx.x, lane = tid & 63, wid = tid >> 6;
    int idx = blockIdx.x * 1024 + tid;
    int v = (idx < n) ? counts[idx] : 0;
    int s = v;
#pragma unroll
    for (int off = 1; off < 64; off <<= 1) {
        int t = __shfl_up(s, off);
        if (lane >= off) s += t;
    }
    if (lane == 63) ws[wid] = s;
    __syncthreads();
    if (tid < 16) {
        int w2 = ws[tid];
#pragma unroll
        for (int off = 1; off < 16; off <<= 1) {
            int t = __shfl_up(w2, off);
            if (tid >= off) w2 += t;
        }
        ws[tid] = w2;
    }
    __syncthreads();
    int wpre = wid ? ws[wid - 1] : 0;
    if (idx < n) offsets[idx] = wpre + s - v;  // block-local exclusive
    if (tid == 0) bsums[blockIdx.x] = ws[15];
}

__global__ void scan_sums(int* bsums, int nb) {
    int lane = threadIdx.x;  // 64 threads, 1 wave
    int v = (lane < nb) ? bsums[lane] : 0;
    int s = v;
#pragma unroll
    for (int off = 1; off < 64; off <<= 1) {
        int t = __shfl_up(s, off);
        if (lane >= off) s += t;
    }
    if (lane < nb) bsums[lane] = s - v;  // exclusive
}

__global__ __launch_bounds__(1024) void add_off(const int* __restrict__ bsums,
                                                int* __restrict__ offsets, int n, int e) {
    int idx = blockIdx.x * 1024 + threadIdx.x;
    if (idx < n) offsets[idx] += bsums[blockIdx.x];
    if (idx == 0) offsets[n] = e;
}

__global__ void copy_int_kernel(const int* __restrict__ a, int* __restrict__ b, int n) {
    int i = blockIdx.x * blockDim.x + threadIdx.x;
    if (i < n) b[i] = a[i];
}

__global__ void scatter_kernel(const int* __restrict__ src, const int* __restrict__ dst,
                               int* __restrict__ cursor, int* __restrict__ csr_src, int e) {
    int i = blockIdx.x * blockDim.x + threadIdx.x;
    if (i < e) {
        int pos = atomicAdd(&cursor[dst[i]], 1);
        csr_src[pos] = src[i];
    }
}

// ---------------- per-node edge softmax + aggregate (single pass, online max) ------------
// one wave per node. H==4: lane owns feats [lane*4, lane*4+4), head = lane>>4 (one 8B gather
// per edge per lane). H==1: lane owns feat `lane`, head 0.
template<int H, bool RES, int ACT, bool OUT_BF16>
__global__ __launch_bounds__(256) void gat_agg(const __hip_bfloat16* __restrict__ feat,
                                               const float* __restrict__ el,
                                               const float* __restrict__ er,
                                               const int* __restrict__ offsets,
                                               const int* __restrict__ csr_src,
                                               const __hip_bfloat16* __restrict__ resid,
                                               void* __restrict__ outv, int n) {
    const int D = H * 64;
    int node = blockIdx.x * 4 + (threadIdx.x >> 6);
    int lane = threadIdx.x & 63;
    if (node >= n) return;
    int e0 = offsets[node], e1 = offsets[node + 1];
    const int head = (H == 4) ? (lane >> 4) : 0;
    float erh = er[(size_t)node * H + head];

    float m = -INFINITY, den = 0.f;
    float acc[4] = {0.f, 0.f, 0.f, 0.f};
    const unsigned short* fp = (const unsigned short*)feat;

#define STEP(LV, UX, UY)                                                \
    {                                                                   \
        float xx = leakyf((LV) + erh);                                  \
        float mn = fmaxf(m, xx);                                        \
        float rs = __expf(m - mn);                                      \
        float w = __expf(xx - mn);                                      \
        m = mn;                                                         \
        den = den * rs + w;                                             \
        acc[0] = acc[0] * rs + w * bflo(UX);                            \
        if (H == 4) {                                                   \
            acc[1] = acc[1] * rs + w * bfhi(UX);                        \
            acc[2] = acc[2] * rs + w * bflo(UY);                        \
            acc[3] = acc[3] * rs + w * bfhi(UY);                        \
        }                                                               \
    }

    int e = e0;
    for (; e + 2 <= e1; e += 2) {
        int s0 = csr_src[e], s1 = csr_src[e + 1];
        float l0 = el[(size_t)s0 * H + head];
        float l1 = el[(size_t)s1 * H + head];
        unsigned ux0, uy0 = 0, ux1, uy1 = 0;
        if (H == 4) {
            uint2 u0 = *(const uint2*)(fp + (size_t)s0 * D + lane * 4);
            uint2 u1 = *(const uint2*)(fp + (size_t)s1 * D + lane * 4);
            ux0 = u0.x; uy0 = u0.y; ux1 = u1.x; uy1 = u1.y;
        } else {
            ux0 = fp[(size_t)s0 * D + lane];
            ux1 = fp[(size_t)s1 * D + lane];
        }
        STEP(l0, ux0, uy0);
        STEP(l1, ux1, uy1);
    }
    if (e < e1) {
        int s0 = csr_src[e];
        float l0 = el[(size_t)s0 * H + head];
        unsigned ux0, uy0 = 0;
        if (H == 4) {
            uint2 u0 = *(const uint2*)(fp + (size_t)s0 * D + lane * 4);
            ux0 = u0.x; uy0 = u0.y;
        } else {
            ux0 = fp[(size_t)s0 * D + lane];
        }
        STEP(l0, ux0, uy0);
    }
#undef STEP

    float inv = den > 0.f ? 1.f / den : 0.f;
    float v[4];
#pragma unroll
    for (int i = 0; i < 4; ++i) v[i] = acc[i] * inv;

    if (RES) {
        if (H == 4) {
            uint2 ru = *(const uint2*)((const unsigned short*)resid + (size_t)node * D + lane * 4);
            v[0] += bflo(ru.x); v[1] += bfhi(ru.x); v[2] += bflo(ru.y); v[3] += bfhi(ru.y);
        } else {
            v[0] += bflo(((const unsigned short*)resid)[(size_t)node * D + lane]);
        }
    }
    if (ACT == 1) {
#pragma unroll
        for (int i = 0; i < 4; ++i) v[i] = v[i] > 0.f ? v[i] : __expf(v[i]) - 1.f;
    }
    if (OUT_BF16) {
        if (H == 4) {
            bf16x4 o = {__float2bfloat16(v[0]), __float2bfloat16(v[1]),
                        __float2bfloat16(v[2]), __float2bfloat16(v[3])};
            *(bf16x4*)((__hip_bfloat16*)outv + (size_t)node * D + lane * 4) = o;
        } else {
            ((__hip_bfloat16*)outv)[(size_t)node * D + lane] = __float2bfloat16(v[0]);
        }
    } else {
        if (H == 4) {
#pragma unroll
            for (int i = 0; i < 4; ++i)
                ((float*)outv)[(size_t)node * D + lane * 4 + i] = v[i];
        } else {
            ((float*)outv)[(size_t)node * D + lane] = v[0];
        }
    }
}

// ---------------- launcher ----------------------------------------------------------------
extern "C" void kernel_launch(void* const* d_in, const int* in_sizes, int n_in,
                              void* d_out, int out_size, void* d_ws, size_t ws_size,
                              hipStream_t stream) {
    const float* x      = (const float*)d_in[0];
    const float* W1     = (const float*)d_in[1];
    const float* al1    = (const float*)d_in[2];
    const float* ar1    = (const float*)d_in[3];
    const float* W2     = (const float*)d_in[4];
    const float* al2    = (const float*)d_in[5];
    const float* ar2    = (const float*)d_in[6];
    const float* W3     = (const float*)d_in[7];
    const float* al3    = (const float*)d_in[8];
    const float* ar3    = (const float*)d_in[9];
    const float* res_W3 = (const float*)d_in[10];
    const int*   src    = (const int*)d_in[11];
    const int*   dst    = (const int*)d_in[12];

    const int N = in_sizes[0] / 128;    // 50000
    const int E = in_sizes[11];         // 500000

    float* out = (float*)d_out;

    // workspace layout (bf16 = 2B)
    __hip_bfloat16* xb    = (__hip_bfloat16*)d_ws;          // [N,128]
    __hip_bfloat16* featb = xb + (size_t)N * 128;           // [N,256]
    __hip_bfloat16* h1    = featb + (size_t)N * 256;        // [N,256]
    __hip_bfloat16* h2    = h1 + (size_t)N * 256;           // [N,256]
    __hip_bfloat16* W1t   = h2 + (size_t)N * 256;           // [256,128]
    __hip_bfloat16* W2t   = W1t + 128 * 256;                // [256,256]
    __hip_bfloat16* W3t   = W2t + 256 * 256;                // [64,256]
    __hip_bfloat16* RW3t  = W3t + 256 * 64;                 // [64,256]
    float* el = (float*)(RW3t + 256 * 64);                  // [N,4]
    float* er = el + (size_t)N * 4;                         // [N,4]
    int* offsets = (int*)(er + (size_t)N * 4);              // [N+1]
    int* cursor  = offsets + (N + 1);                       // [N]
    int* csr_src = cursor + N;                              // [E]
    int* bsums   = csr_src + E;                             // [64]

    const int T = 256;
    const int scan_blocks = (N + 1023) / 1024;

    // ---- conversions ----
    cvt_bf16<<<(N * 128 / 4 + T - 1) / T, T, 0, stream>>>(x, xb, N * 128);
    tconv<<<(128 * 256 + T - 1) / T, T, 0, stream>>>(W1, W1t, 128, 256);
    tconv<<<(256 * 256 + T - 1) / T, T, 0, stream>>>(W2, W2t, 256, 256);
    tconv<<<(256 * 64 + T - 1) / T, T, 0, stream>>>(W3, W3t, 256, 64);
    tconv<<<(256 * 64 + T - 1) / T, T, 0, stream>>>(res_W3, RW3t, 256, 64);

    // ---- CSR by dst ----
    hipMemsetAsync(cursor, 0, (size_t)N * sizeof(int), stream);
    hist_kernel<<<(E + T - 1) / T, T, 0, stream>>>(dst, cursor, E);
    scan_block<<<scan_blocks, 1024, 0, stream>>>(cursor, offsets, bsums, N);
    scan_sums<<<1, 64, 0, stream>>>(bsums, scan_blocks);
    add_off<<<scan_blocks, 1024, 0, stream>>>(bsums, offsets, N, E);
    copy_int_kernel<<<(N + T - 1) / T, T, 0, stream>>>(offsets, cursor, N);
    scatter_kernel<<<(E + T - 1) / T, T, 0, stream>>>(src, dst, cursor, csr_src, E);

    int gemm4_blocks = (N + 63) / 64;
    int gemm1_blocks = (N + 255) / 256;
    int node_blocks = (N + 3) / 4;

    // ---- Layer 1: feat = xb @ W1 (+el/er) ; agg -> h1 (elu, bf16) ----
    gemm_bf16<4, false, true, true><<<gemm4_blocks, T, 0, stream>>>(xb, W1t, featb, al1, ar1, el, er, N, 128);
    gat_agg<4, false, 1, true><<<node_blocks, T, 0, stream>>>(featb, el, er, offsets, csr_src, nullptr, h1, N);

    // ---- Layer 2: feat = h1 @ W2 (+el/er) ; agg + resid(h1) -> h2 (elu, bf16) ----
    gemm_bf16<4, false, true, true><<<gemm4_blocks, T, 0, stream>>>(h1, W2t, featb, al2, ar2, el, er, N, 256);
    gat_agg<4, true, 1, true><<<node_blocks, T, 0, stream>>>(featb, el, er, offsets, csr_src, h1, h2, N);

    // ---- Layer 3: feat = h2 @ W3 (+el/er) ; agg -> out (f32) ; out += h2 @ res_W3 ----
    gemm_bf16<1, false, true, true><<<gemm1_blocks, T, 0, stream>>>(h2, W3t, featb, al3, ar3, el, er, N, 256);
    gat_agg<1, false, 0, false><<<node_blocks, T, 0, stream>>>(featb, el, er, offsets, csr_src, nullptr, out, N);
    gemm_bf16<1, true, false, false><<<gemm1_blocks, T, 0, stream>>>(h2, RW3t, out, nullptr, nullptr, nullptr, nullptr, N, 256);
}

// Round 4
// 291.666 us; speedup vs baseline: 2.8609x; 1.0711x over previous
//
#include <hip/hip_runtime.h>
#include <hip/hip_bf16.h>
#include <math.h>

#define SLOPE 0.2f

typedef __attribute__((ext_vector_type(8))) short short8;
typedef __attribute__((ext_vector_type(4))) float f32x4;

static __device__ __forceinline__ float leakyf(float x) { return x >= 0.f ? x : SLOPE * x; }
static __device__ __forceinline__ float bflo(unsigned u) { return __builtin_bit_cast(float, u << 16); }
static __device__ __forceinline__ float bfhi(unsigned u) { return __builtin_bit_cast(float, u & 0xffff0000u); }
static __device__ __forceinline__ unsigned short f2bf(float f) {
    unsigned u = __builtin_bit_cast(unsigned, f);
    return (unsigned short)((u + 0x7fff + ((u >> 16) & 1)) >> 16);  // RNE
}

struct __align__(8) us4 { unsigned short a, b, c, d; };

// ---------------- weight transpose+convert: Wt[n][k] = W[k][n] ---------------------------
__global__ void tconv(const float* __restrict__ W, unsigned short* __restrict__ Wt, int K, int Nc) {
    int i = blockIdx.x * blockDim.x + threadIdx.x;
    if (i < K * Nc) {
        int k = i / Nc, n = i - k * Nc;
        Wt[(size_t)n * K + k] = f2bf(W[i]);
    }
}

// ---------------- MFMA GEMM (layers 1/2) + fused attention projections -------------------
// Nc=256. Block covers 64 rows; wave w = col stripe [w*64, +64) = head w.
// A_F32: A is f32 (layer 1 input), convert fragments in-register.
template<bool A_F32>
__global__ __launch_bounds__(256) void gemm_l12(const void* __restrict__ Av,
                                                const unsigned short* __restrict__ Wt,
                                                unsigned short* __restrict__ outb,
                                                const float* __restrict__ al,
                                                const float* __restrict__ ar,
                                                float* __restrict__ el,
                                                float* __restrict__ er,
                                                int M, int K) {
    const int lane = threadIdx.x & 63;
    const int wid = threadIdx.x >> 6;       // head
    const int rlo = lane & 15;
    const int q = lane >> 4;
    const int kg = q * 8;
    const int m0 = blockIdx.x * 64;
    const int cbase = wid * 64;

    f32x4 acc[4][4];
#pragma unroll
    for (int mf = 0; mf < 4; ++mf)
#pragma unroll
        for (int nf = 0; nf < 4; ++nf) acc[mf][nf] = (f32x4){0.f, 0.f, 0.f, 0.f};

    for (int k0 = 0; k0 < K; k0 += 32) {
        short8 a[4];
#pragma unroll
        for (int mf = 0; mf < 4; ++mf) {
            int r = m0 + mf * 16 + rlo;
            if (r >= M) r = M - 1;  // clamp; affects only unstored rows
            if (A_F32) {
                const float* ap = (const float*)Av + (size_t)r * K + k0 + kg;
                float4 f0 = *(const float4*)ap;
                float4 f1 = *(const float4*)(ap + 4);
                short8 t;
                t[0] = f2bf(f0.x); t[1] = f2bf(f0.y); t[2] = f2bf(f0.z); t[3] = f2bf(f0.w);
                t[4] = f2bf(f1.x); t[5] = f2bf(f1.y); t[6] = f2bf(f1.z); t[7] = f2bf(f1.w);
                a[mf] = t;
            } else {
                a[mf] = *(const short8*)((const unsigned short*)Av + (size_t)r * K + k0 + kg);
            }
        }
#pragma unroll
        for (int nf = 0; nf < 4; ++nf) {
            short8 b = *(const short8*)(Wt + (size_t)(cbase + nf * 16 + rlo) * K + k0 + kg);
#pragma unroll
            for (int mf = 0; mf < 4; ++mf)
                acc[mf][nf] = __builtin_amdgcn_mfma_f32_16x16x32_bf16(a[mf], b, acc[mf][nf], 0, 0, 0);
        }
    }

    float alv[4], arv[4];
#pragma unroll
    for (int nf = 0; nf < 4; ++nf) {
        alv[nf] = al[cbase + nf * 16 + rlo];
        arv[nf] = ar[cbase + nf * 16 + rlo];
    }

#pragma unroll
    for (int mf = 0; mf < 4; ++mf) {
#pragma unroll
        for (int reg = 0; reg < 4; ++reg) {
            int r = m0 + mf * 16 + q * 4 + reg;
            float pl = 0.f, pr = 0.f;
#pragma unroll
            for (int nf = 0; nf < 4; ++nf) {
                pl += acc[mf][nf][reg] * alv[nf];
                pr += acc[mf][nf][reg] * arv[nf];
            }
#pragma unroll
            for (int off = 1; off < 16; off <<= 1) {
                pl += __shfl_xor(pl, off);
                pr += __shfl_xor(pr, off);
            }
            if (rlo == 0 && r < M) {
                el[(size_t)r * 4 + wid] = pl;
                er[(size_t)r * 4 + wid] = pr;
            }
            if (r < M) {
#pragma unroll
                for (int nf = 0; nf < 4; ++nf)
                    outb[(size_t)r * 256 + cbase + nf * 16 + rlo] = f2bf(acc[mf][nf][reg]);
            }
        }
    }
}

// ---------------- layer-3 fused GEMM: h2 @ [W3 | res_W3] ---------------------------------
// Block: 128 rows x 128 cols, 4 waves. wave w: rows m0+(w>>1)*64, col-half (w&1)*64.
// col-half 0 -> featb (bf16) + el/er (head 0); col-half 1 -> resf (f32).
__global__ __launch_bounds__(256) void gemm_l3(const unsigned short* __restrict__ A,
                                               const unsigned short* __restrict__ Wt,
                                               unsigned short* __restrict__ featb,
                                               float* __restrict__ resf,
                                               const float* __restrict__ al,
                                               const float* __restrict__ ar,
                                               float* __restrict__ el,
                                               float* __restrict__ er, int M) {
    const int K = 256;
    const int lane = threadIdx.x & 63;
    const int wid = threadIdx.x >> 6;
    const int rlo = lane & 15;
    const int q = lane >> 4;
    const int kg = q * 8;
    const int m0 = blockIdx.x * 128 + (wid >> 1) * 64;
    const int ch = wid & 1;
    const int cbase = ch * 64;

    f32x4 acc[4][4];
#pragma unroll
    for (int mf = 0; mf < 4; ++mf)
#pragma unroll
        for (int nf = 0; nf < 4; ++nf) acc[mf][nf] = (f32x4){0.f, 0.f, 0.f, 0.f};

    for (int k0 = 0; k0 < K; k0 += 32) {
        short8 a[4];
#pragma unroll
        for (int mf = 0; mf < 4; ++mf) {
            int r = m0 + mf * 16 + rlo;
            if (r >= M) r = M - 1;
            a[mf] = *(const short8*)(A + (size_t)r * K + k0 + kg);
        }
#pragma unroll
        for (int nf = 0; nf < 4; ++nf) {
            short8 b = *(const short8*)(Wt + (size_t)(cbase + nf * 16 + rlo) * K + k0 + kg);
#pragma unroll
            for (int mf = 0; mf < 4; ++mf)
                acc[mf][nf] = __builtin_amdgcn_mfma_f32_16x16x32_bf16(a[mf], b, acc[mf][nf], 0, 0, 0);
        }
    }

    float alv[4], arv[4];
    if (ch == 0) {
#pragma unroll
        for (int nf = 0; nf < 4; ++nf) {
            alv[nf] = al[nf * 16 + rlo];
            arv[nf] = ar[nf * 16 + rlo];
        }
    }

#pragma unroll
    for (int mf = 0; mf < 4; ++mf) {
#pragma unroll
        for (int reg = 0; reg < 4; ++reg) {
            int r = m0 + mf * 16 + q * 4 + reg;
            if (ch == 0) {
                float pl = 0.f, pr = 0.f;
#pragma unroll
                for (int nf = 0; nf < 4; ++nf) {
                    pl += acc[mf][nf][reg] * alv[nf];
                    pr += acc[mf][nf][reg] * arv[nf];
                }
#pragma unroll
                for (int off = 1; off < 16; off <<= 1) {
                    pl += __shfl_xor(pl, off);
                    pr += __shfl_xor(pr, off);
                }
                if (rlo == 0 && r < M) { el[r] = pl; er[r] = pr; }
                if (r < M) {
#pragma unroll
                    for (int nf = 0; nf < 4; ++nf)
                        featb[(size_t)r * 64 + nf * 16 + rlo] = f2bf(acc[mf][nf][reg]);
                }
            } else if (r < M) {
#pragma unroll
                for (int nf = 0; nf < 4; ++nf)
                    resf[(size_t)r * 64 + nf * 16 + rlo] = acc[mf][nf][reg];
            }
        }
    }
}

// ---------------- CSR build --------------------------------------------------------------
__global__ void hist_kernel(const int* __restrict__ dst, int* __restrict__ counts, int e) {
    int i = blockIdx.x * blockDim.x + threadIdx.x;
    if (i < e) atomicAdd(&counts[dst[i]], 1);
}

__global__ __launch_bounds__(1024) void scan_block(const int* __restrict__ counts,
                                                   int* __restrict__ offsets,
                                                   int* __restrict__ bsums, int n) {
    __shared__ int ws[16];
    int tid = threadIdx.x, lane = tid & 63, wid = tid >> 6;
    int idx = blockIdx.x * 1024 + tid;
    int v = (idx < n) ? counts[idx] : 0;
    int s = v;
#pragma unroll
    for (int off = 1; off < 64; off <<= 1) {
        int t = __shfl_up(s, off);
        if (lane >= off) s += t;
    }
    if (lane == 63) ws[wid] = s;
    __syncthreads();
    if (tid < 16) {
        int w2 = ws[tid];
#pragma unroll
        for (int off = 1; off < 16; off <<= 1) {
            int t = __shfl_up(w2, off);
            if (tid >= off) w2 += t;
        }
        ws[tid] = w2;
    }
    __syncthreads();
    int wpre = wid ? ws[wid - 1] : 0;
    if (idx < n) offsets[idx] = wpre + s - v;
    if (tid == 0) bsums[blockIdx.x] = ws[15];
}

__global__ void scan_sums(int* bsums, int nb) {
    int lane = threadIdx.x;
    int v = (lane < nb) ? bsums[lane] : 0;
    int s = v;
#pragma unroll
    for (int off = 1; off < 64; off <<= 1) {
        int t = __shfl_up(s, off);
        if (lane >= off) s += t;
    }
    if (lane < nb) bsums[lane] = s - v;
}

__global__ __launch_bounds__(1024) void add_off(const int* __restrict__ bsums,
                                                int* __restrict__ offsets,
                                                int* __restrict__ cursor, int n, int e) {
    int idx = blockIdx.x * 1024 + threadIdx.x;
    if (idx < n) {
        int v = offsets[idx] + bsums[blockIdx.x];
        offsets[idx] = v;
        cursor[idx] = v;
    }
    if (idx == 0) offsets[n] = e;
}

__global__ void scatter_kernel(const int* __restrict__ src, const int* __restrict__ dst,
                               int* __restrict__ cursor, int* __restrict__ csr_src, int e) {
    int i = blockIdx.x * blockDim.x + threadIdx.x;
    if (i < e) {
        int pos = atomicAdd(&cursor[dst[i]], 1);
        csr_src[pos] = src[i];
    }
}

// ---------------- per-node edge softmax + aggregate (no-max exp, 4-edge batch) -----------
// one wave per node. H==4: lane owns feats [lane*4,+4), head=lane>>4. H==1: lane owns feat lane.
// RES: 0 none, 1 bf16 resid, 2 f32 resid. ACT: 0 none, 1 elu.
template<int H, int RES, int ACT, bool OUT_BF16>
__global__ __launch_bounds__(256) void gat_agg(const unsigned short* __restrict__ fp,
                                               const float* __restrict__ el,
                                               const float* __restrict__ er,
                                               const int* __restrict__ offsets,
                                               const int* __restrict__ csr_src,
                                               const void* __restrict__ resid,
                                               void* __restrict__ outv, int n) {
    const int D = H * 64;
    int node = blockIdx.x * 4 + (threadIdx.x >> 6);
    int lane = threadIdx.x & 63;
    if (node >= n) return;
    int e0 = offsets[node], e1 = offsets[node + 1];
    const int head = (H == 4) ? (lane >> 4) : 0;
    float erh = er[(size_t)node * H + head];

    float denA = 0.f, denB = 0.f;
    float accA[4] = {0.f, 0.f, 0.f, 0.f};
    float accB[4] = {0.f, 0.f, 0.f, 0.f};

#define STEP(DEN, AC, LV, UX, UY)                                      \
    {                                                                  \
        float xx = fminf(leakyf((LV) + erh), 80.f);                    \
        float w = __expf(xx);                                          \
        DEN += w;                                                      \
        AC[0] += w * bflo(UX);                                         \
        if (H == 4) {                                                  \
            AC[1] += w * bfhi(UX);                                     \
            AC[2] += w * bflo(UY);                                     \
            AC[3] += w * bfhi(UY);                                     \
        }                                                              \
    }

    int e = e0;
    for (; e + 4 <= e1; e += 4) {
        int s0 = csr_src[e], s1 = csr_src[e + 1], s2 = csr_src[e + 2], s3 = csr_src[e + 3];
        float l0 = el[(size_t)s0 * H + head];
        float l1 = el[(size_t)s1 * H + head];
        float l2 = el[(size_t)s2 * H + head];
        float l3 = el[(size_t)s3 * H + head];
        unsigned x0, y0 = 0, x1, y1 = 0, x2, y2 = 0, x3, y3 = 0;
        if (H == 4) {
            uint2 u0 = *(const uint2*)(fp + (size_t)s0 * D + lane * 4);
            uint2 u1 = *(const uint2*)(fp + (size_t)s1 * D + lane * 4);
            uint2 u2 = *(const uint2*)(fp + (size_t)s2 * D + lane * 4);
            uint2 u3 = *(const uint2*)(fp + (size_t)s3 * D + lane * 4);
            x0 = u0.x; y0 = u0.y; x1 = u1.x; y1 = u1.y;
            x2 = u2.x; y2 = u2.y; x3 = u3.x; y3 = u3.y;
        } else {
            x0 = fp[(size_t)s0 * D + lane];
            x1 = fp[(size_t)s1 * D + lane];
            x2 = fp[(size_t)s2 * D + lane];
            x3 = fp[(size_t)s3 * D + lane];
        }
        STEP(denA, accA, l0, x0, y0);
        STEP(denB, accB, l1, x1, y1);
        STEP(denA, accA, l2, x2, y2);
        STEP(denB, accB, l3, x3, y3);
    }
    for (; e < e1; ++e) {
        int s0 = csr_src[e];
        float l0 = el[(size_t)s0 * H + head];
        unsigned x0, y0 = 0;
        if (H == 4) {
            uint2 u0 = *(const uint2*)(fp + (size_t)s0 * D + lane * 4);
            x0 = u0.x; y0 = u0.y;
        } else {
            x0 = fp[(size_t)s0 * D + lane];
        }
        STEP(denA, accA, l0, x0, y0);
    }
#undef STEP

    float den = denA + denB;
    float inv = den > 0.f ? 1.f / den : 0.f;
    float v[4];
#pragma unroll
    for (int i = 0; i < 4; ++i) v[i] = (accA[i] + accB[i]) * inv;

    if (RES == 1) {
        uint2 ru = *(const uint2*)((const unsigned short*)resid + (size_t)node * D + lane * 4);
        v[0] += bflo(ru.x); v[1] += bfhi(ru.x); v[2] += bflo(ru.y); v[3] += bfhi(ru.y);
    } else if (RES == 2) {
        v[0] += ((const float*)resid)[(size_t)node * D + lane];
    }
    if (ACT == 1) {
#pragma unroll
        for (int i = 0; i < 4; ++i) v[i] = v[i] > 0.f ? v[i] : __expf(v[i]) - 1.f;
    }
    if (OUT_BF16) {
        if (H == 4) {
            us4 o = {f2bf(v[0]), f2bf(v[1]), f2bf(v[2]), f2bf(v[3])};
            *(us4*)((unsigned short*)outv + (size_t)node * D + lane * 4) = o;
        } else {
            ((unsigned short*)outv)[(size_t)node * D + lane] = f2bf(v[0]);
        }
    } else {
        if (H == 4) {
            float4 o = {v[0], v[1], v[2], v[3]};
            *(float4*)((float*)outv + (size_t)node * D + lane * 4) = o;
        } else {
            ((float*)outv)[(size_t)node * D + lane] = v[0];
        }
    }
}

// ---------------- launcher ----------------------------------------------------------------
extern "C" void kernel_launch(void* const* d_in, const int* in_sizes, int n_in,
                              void* d_out, int out_size, void* d_ws, size_t ws_size,
                              hipStream_t stream) {
    const float* x      = (const float*)d_in[0];
    const float* W1     = (const float*)d_in[1];
    const float* al1    = (const float*)d_in[2];
    const float* ar1    = (const float*)d_in[3];
    const float* W2     = (const float*)d_in[4];
    const float* al2    = (const float*)d_in[5];
    const float* ar2    = (const float*)d_in[6];
    const float* W3     = (const float*)d_in[7];
    const float* al3    = (const float*)d_in[8];
    const float* ar3    = (const float*)d_in[9];
    const float* res_W3 = (const float*)d_in[10];
    const int*   src    = (const int*)d_in[11];
    const int*   dst    = (const int*)d_in[12];

    const int N = in_sizes[0] / 128;    // 50000
    const int E = in_sizes[11];         // 500000

    float* out = (float*)d_out;

    // workspace layout
    unsigned short* featb = (unsigned short*)d_ws;          // [N,256] (layer3: [N,64])
    unsigned short* h1    = featb + (size_t)N * 256;        // [N,256]
    unsigned short* h2    = h1 + (size_t)N * 256;           // [N,256]
    unsigned short* W1t   = h2 + (size_t)N * 256;           // [256,128]
    unsigned short* W2t   = W1t + 256 * 128;                // [256,256]
    unsigned short* W3c   = W2t + 256 * 256;                // [128,256] = [W3t | RW3t]
    float* resf = (float*)(W3c + 128 * 256);                // [N,64]
    float* el   = resf + (size_t)N * 64;                    // [N,4]
    float* er   = el + (size_t)N * 4;                       // [N,4]
    int* offsets = (int*)(er + (size_t)N * 4);              // [N+1]
    int* cursor  = offsets + (N + 1);                       // [N]
    int* csr_src = cursor + N;                              // [E]
    int* bsums   = csr_src + E;                             // [64]

    const int T = 256;
    const int scan_blocks = (N + 1023) / 1024;

    // ---- weight conversions ----
    tconv<<<(128 * 256 + T - 1) / T, T, 0, stream>>>(W1, W1t, 128, 256);
    tconv<<<(256 * 256 + T - 1) / T, T, 0, stream>>>(W2, W2t, 256, 256);
    tconv<<<(256 * 64 + T - 1) / T, T, 0, stream>>>(W3, W3c, 256, 64);
    tconv<<<(256 * 64 + T - 1) / T, T, 0, stream>>>(res_W3, W3c + 64 * 256, 256, 64);

    // ---- CSR by dst ----
    hipMemsetAsync(cursor, 0, (size_t)N * sizeof(int), stream);
    hist_kernel<<<(E + T - 1) / T, T, 0, stream>>>(dst, cursor, E);
    scan_block<<<scan_blocks, 1024, 0, stream>>>(cursor, offsets, bsums, N);
    scan_sums<<<1, 64, 0, stream>>>(bsums, scan_blocks);
    add_off<<<scan_blocks, 1024, 0, stream>>>(bsums, offsets, cursor, N, E);
    scatter_kernel<<<(E + T - 1) / T, T, 0, stream>>>(src, dst, cursor, csr_src, E);

    int gemm12_blocks = (N + 63) / 64;
    int gemm3_blocks = (N + 127) / 128;
    int node_blocks = (N + 3) / 4;

    // ---- Layer 1: feat = x(f32) @ W1 (+el/er) ; agg -> h1 (elu, bf16) ----
    gemm_l12<true><<<gemm12_blocks, T, 0, stream>>>(x, W1t, featb, al1, ar1, el, er, N, 128);
    gat_agg<4, 0, 1, true><<<node_blocks, T, 0, stream>>>(featb, el, er, offsets, csr_src, nullptr, h1, N);

    // ---- Layer 2: feat = h1 @ W2 (+el/er) ; agg + resid(h1) -> h2 (elu, bf16) ----
    gemm_l12<false><<<gemm12_blocks, T, 0, stream>>>(h1, W2t, featb, al2, ar2, el, er, N, 256);
    gat_agg<4, 1, 1, true><<<node_blocks, T, 0, stream>>>(featb, el, er, offsets, csr_src, h1, h2, N);

    // ---- Layer 3: [feat|res] = h2 @ [W3|res_W3] (+el/er) ; agg + res -> out (f32) ----
    gemm_l3<<<gemm3_blocks, T, 0, stream>>>(h2, W3c, featb, resf, al3, ar3, el, er, N);
    gat_agg<1, 2, 0, false><<<node_blocks, T, 0, stream>>>(featb, el, er, offsets, csr_src, resf, out, N);
}

// Round 5
// 284.857 us; speedup vs baseline: 2.9293x; 1.0239x over previous
//
#include <hip/hip_runtime.h>
#include <hip/hip_bf16.h>
#include <math.h>

#define SLOPE 0.2f

typedef __attribute__((ext_vector_type(8))) short short8;
typedef __attribute__((ext_vector_type(4))) float f32x4;

static __device__ __forceinline__ float leakyf(float x) { return x >= 0.f ? x : SLOPE * x; }
static __device__ __forceinline__ float bflo(unsigned u) { return __builtin_bit_cast(float, u << 16); }
static __device__ __forceinline__ float bfhi(unsigned u) { return __builtin_bit_cast(float, u & 0xffff0000u); }
static __device__ __forceinline__ unsigned short f2bf(float f) {
    unsigned u = __builtin_bit_cast(unsigned, f);
    return (unsigned short)((u + 0x7fff + ((u >> 16) & 1)) >> 16);  // RNE
}

struct __align__(8) us4 { unsigned short a, b, c, d; };

// ---------------- fused weight transpose+convert (one dispatch for all 4 weights) --------
// W1:128x256 -> W1t[256][128]; W2:256x256 -> W2t[256][256]; W3:256x64 -> W3c[0..64);
// res_W3:256x64 -> W3c[64..128). All Wt[n][k] = W[k][n].
__global__ __launch_bounds__(256) void tconv_all(const float* __restrict__ W1,
                                                 const float* __restrict__ W2,
                                                 const float* __restrict__ W3,
                                                 const float* __restrict__ rW3,
                                                 unsigned short* __restrict__ W1t,
                                                 unsigned short* __restrict__ W2t,
                                                 unsigned short* __restrict__ W3c) {
    int i = blockIdx.x * 256 + threadIdx.x;
    const float* W; unsigned short* Wt; int K, lNc, idx;
    if (i < 32768)       { W = W1;  Wt = W1t;            K = 128; lNc = 8; idx = i; }
    else if (i < 98304)  { W = W2;  Wt = W2t;            K = 256; lNc = 8; idx = i - 32768; }
    else if (i < 114688) { W = W3;  Wt = W3c;            K = 256; lNc = 6; idx = i - 98304; }
    else                 { W = rW3; Wt = W3c + 64 * 256; K = 256; lNc = 6; idx = i - 114688; }
    int k = idx >> lNc, n = idx & ((1 << lNc) - 1);
    Wt[n * K + k] = f2bf(W[idx]);
}

// ---------------- MFMA GEMM (layers 1/2) + fused attention projections -------------------
template<bool A_F32>
__global__ __launch_bounds__(256) void gemm_l12(const void* __restrict__ Av,
                                                const unsigned short* __restrict__ Wt,
                                                unsigned short* __restrict__ outb,
                                                const float* __restrict__ al,
                                                const float* __restrict__ ar,
                                                float* __restrict__ el,
                                                float* __restrict__ er,
                                                int M, int K) {
    const int lane = threadIdx.x & 63;
    const int wid = threadIdx.x >> 6;       // head
    const int rlo = lane & 15;
    const int q = lane >> 4;
    const int kg = q * 8;
    const int m0 = blockIdx.x * 64;
    const int cbase = wid * 64;

    f32x4 acc[4][4];
#pragma unroll
    for (int mf = 0; mf < 4; ++mf)
#pragma unroll
        for (int nf = 0; nf < 4; ++nf) acc[mf][nf] = (f32x4){0.f, 0.f, 0.f, 0.f};

    for (int k0 = 0; k0 < K; k0 += 32) {
        short8 a[4];
#pragma unroll
        for (int mf = 0; mf < 4; ++mf) {
            int r = m0 + mf * 16 + rlo;
            if (r >= M) r = M - 1;  // clamp; affects only unstored rows
            if (A_F32) {
                const float* ap = (const float*)Av + (size_t)r * K + k0 + kg;
                float4 f0 = *(const float4*)ap;
                float4 f1 = *(const float4*)(ap + 4);
                short8 t;
                t[0] = f2bf(f0.x); t[1] = f2bf(f0.y); t[2] = f2bf(f0.z); t[3] = f2bf(f0.w);
                t[4] = f2bf(f1.x); t[5] = f2bf(f1.y); t[6] = f2bf(f1.z); t[7] = f2bf(f1.w);
                a[mf] = t;
            } else {
                a[mf] = *(const short8*)((const unsigned short*)Av + (size_t)r * K + k0 + kg);
            }
        }
#pragma unroll
        for (int nf = 0; nf < 4; ++nf) {
            short8 b = *(const short8*)(Wt + (size_t)(cbase + nf * 16 + rlo) * K + k0 + kg);
#pragma unroll
            for (int mf = 0; mf < 4; ++mf)
                acc[mf][nf] = __builtin_amdgcn_mfma_f32_16x16x32_bf16(a[mf], b, acc[mf][nf], 0, 0, 0);
        }
    }

    float alv[4], arv[4];
#pragma unroll
    for (int nf = 0; nf < 4; ++nf) {
        alv[nf] = al[cbase + nf * 16 + rlo];
        arv[nf] = ar[cbase + nf * 16 + rlo];
    }

#pragma unroll
    for (int mf = 0; mf < 4; ++mf) {
#pragma unroll
        for (int reg = 0; reg < 4; ++reg) {
            int r = m0 + mf * 16 + q * 4 + reg;
            float pl = 0.f, pr = 0.f;
#pragma unroll
            for (int nf = 0; nf < 4; ++nf) {
                pl += acc[mf][nf][reg] * alv[nf];
                pr += acc[mf][nf][reg] * arv[nf];
            }
#pragma unroll
            for (int off = 1; off < 16; off <<= 1) {
                pl += __shfl_xor(pl, off);
                pr += __shfl_xor(pr, off);
            }
            if (rlo == 0 && r < M) {
                el[(size_t)r * 4 + wid] = pl;
                er[(size_t)r * 4 + wid] = pr;
            }
            if (r < M) {
#pragma unroll
                for (int nf = 0; nf < 4; ++nf)
                    outb[(size_t)r * 256 + cbase + nf * 16 + rlo] = f2bf(acc[mf][nf][reg]);
            }
        }
    }
}

// ---------------- layer-3 fused GEMM: h2 @ [W3 | res_W3] ---------------------------------
__global__ __launch_bounds__(256) void gemm_l3(const unsigned short* __restrict__ A,
                                               const unsigned short* __restrict__ Wt,
                                               unsigned short* __restrict__ featb,
                                               float* __restrict__ resf,
                                               const float* __restrict__ al,
                                               const float* __restrict__ ar,
                                               float* __restrict__ el,
                                               float* __restrict__ er, int M) {
    const int K = 256;
    const int lane = threadIdx.x & 63;
    const int wid = threadIdx.x >> 6;
    const int rlo = lane & 15;
    const int q = lane >> 4;
    const int kg = q * 8;
    const int m0 = blockIdx.x * 128 + (wid >> 1) * 64;
    const int ch = wid & 1;
    const int cbase = ch * 64;

    f32x4 acc[4][4];
#pragma unroll
    for (int mf = 0; mf < 4; ++mf)
#pragma unroll
        for (int nf = 0; nf < 4; ++nf) acc[mf][nf] = (f32x4){0.f, 0.f, 0.f, 0.f};

    for (int k0 = 0; k0 < K; k0 += 32) {
        short8 a[4];
#pragma unroll
        for (int mf = 0; mf < 4; ++mf) {
            int r = m0 + mf * 16 + rlo;
            if (r >= M) r = M - 1;
            a[mf] = *(const short8*)(A + (size_t)r * K + k0 + kg);
        }
#pragma unroll
        for (int nf = 0; nf < 4; ++nf) {
            short8 b = *(const short8*)(Wt + (size_t)(cbase + nf * 16 + rlo) * K + k0 + kg);
#pragma unroll
            for (int mf = 0; mf < 4; ++mf)
                acc[mf][nf] = __builtin_amdgcn_mfma_f32_16x16x32_bf16(a[mf], b, acc[mf][nf], 0, 0, 0);
        }
    }

    float alv[4], arv[4];
    if (ch == 0) {
#pragma unroll
        for (int nf = 0; nf < 4; ++nf) {
            alv[nf] = al[nf * 16 + rlo];
            arv[nf] = ar[nf * 16 + rlo];
        }
    }

#pragma unroll
    for (int mf = 0; mf < 4; ++mf) {
#pragma unroll
        for (int reg = 0; reg < 4; ++reg) {
            int r = m0 + mf * 16 + q * 4 + reg;
            if (ch == 0) {
                float pl = 0.f, pr = 0.f;
#pragma unroll
                for (int nf = 0; nf < 4; ++nf) {
                    pl += acc[mf][nf][reg] * alv[nf];
                    pr += acc[mf][nf][reg] * arv[nf];
                }
#pragma unroll
                for (int off = 1; off < 16; off <<= 1) {
                    pl += __shfl_xor(pl, off);
                    pr += __shfl_xor(pr, off);
                }
                if (rlo == 0 && r < M) { el[r] = pl; er[r] = pr; }
                if (r < M) {
#pragma unroll
                    for (int nf = 0; nf < 4; ++nf)
                        featb[(size_t)r * 64 + nf * 16 + rlo] = f2bf(acc[mf][nf][reg]);
                }
            } else if (r < M) {
#pragma unroll
                for (int nf = 0; nf < 4; ++nf)
                    resf[(size_t)r * 64 + nf * 16 + rlo] = acc[mf][nf][reg];
            }
        }
    }
}

// ---------------- CSR build --------------------------------------------------------------
__global__ void hist_kernel(const int* __restrict__ dst, int* __restrict__ counts, int e) {
    int i = blockIdx.x * blockDim.x + threadIdx.x;
    if (i < e) atomicAdd(&counts[dst[i]], 1);
}

__global__ __launch_bounds__(1024) void scan_block(const int* __restrict__ counts,
                                                   int* __restrict__ offsets,
                                                   int* __restrict__ bsums, int n) {
    __shared__ int ws[16];
    int tid = threadIdx.x, lane = tid & 63, wid = tid >> 6;
    int idx = blockIdx.x * 1024 + tid;
    int v = (idx < n) ? counts[idx] : 0;
    int s = v;
#pragma unroll
    for (int off = 1; off < 64; off <<= 1) {
        int t = __shfl_up(s, off);
        if (lane >= off) s += t;
    }
    if (lane == 63) ws[wid] = s;
    __syncthreads();
    if (tid < 16) {
        int w2 = ws[tid];
#pragma unroll
        for (int off = 1; off < 16; off <<= 1) {
            int t = __shfl_up(w2, off);
            if (tid >= off) w2 += t;
        }
        ws[tid] = w2;
    }
    __syncthreads();
    int wpre = wid ? ws[wid - 1] : 0;
    if (idx < n) offsets[idx] = wpre + s - v;
    if (tid == 0) bsums[blockIdx.x] = ws[15];
}

// add block base (self-computed reduction over bsums[0..blockIdx); nb <= 64) + init cursor
__global__ __launch_bounds__(1024) void add_off(const int* __restrict__ bsums,
                                                int* __restrict__ offsets,
                                                int* __restrict__ cursor, int n, int e, int nb) {
    __shared__ int base_s;
    int tid = threadIdx.x;
    if (tid < 64) {
        int v = (tid < blockIdx.x && tid < nb) ? bsums[tid] : 0;
#pragma unroll
        for (int off = 32; off > 0; off >>= 1) v += __shfl_xor(v, off);
        if (tid == 0) base_s = v;
    }
    __syncthreads();
    int idx = blockIdx.x * 1024 + tid;
    if (idx < n) {
        int v = offsets[idx] + base_s;
        offsets[idx] = v;
        cursor[idx] = v;
    }
    if (idx == 0) offsets[n] = e;
}

__global__ void scatter_kernel(const int* __restrict__ src, const int* __restrict__ dst,
                               int* __restrict__ cursor, int* __restrict__ csr_src, int e) {
    int i = blockIdx.x * blockDim.x + threadIdx.x;
    if (i < e) {
        int pos = atomicAdd(&cursor[dst[i]], 1);
        csr_src[pos] = src[i];
    }
}

// ---------------- per-node edge softmax + aggregate: two-phase score/gather --------------
// One wave per node. Chunked: score phase is lane-parallel over (edge,head) -> LDS;
// aggregate phase reads w (broadcast) + s from LDS and does pure gather+FMA.
// H==4: chunk=16 edges, lane (j=lane>>2, h=lane&3); feature lane owns feats [lane*4,+4),
//       head=lane>>4. H==1: chunk=64, j=lane; feature lane owns feat `lane`.
// RES: 0 none, 1 bf16 resid, 2 f32 resid. ACT: 0 none, 1 elu.
template<int H, int RES, int ACT, bool OUT_BF16>
__global__ __launch_bounds__(256) void gat_agg(const unsigned short* __restrict__ fp,
                                               const float* __restrict__ el,
                                               const float* __restrict__ er,
                                               const int* __restrict__ offsets,
                                               const int* __restrict__ csr_src,
                                               const void* __restrict__ resid,
                                               void* __restrict__ outv, int n) {
    const int D = H * 64;
    const int CH = (H == 4) ? 16 : 64;
    __shared__ float lw[4][64];
    __shared__ int ls[4][64];
    int node = blockIdx.x * 4 + (threadIdx.x >> 6);
    int lane = threadIdx.x & 63;
    int wv = threadIdx.x >> 6;
    if (node >= n) return;
    int e0 = offsets[node], e1 = offsets[node + 1];
    const int hs = (H == 4) ? (lane & 3) : 0;      // score-phase head
    const int hf = (H == 4) ? (lane >> 4) : 0;     // feature-phase head
    const int js = (H == 4) ? (lane >> 2) : lane;  // score-phase edge slot
    float er_s = er[(size_t)node * H + hs];

    float den = 0.f;
    float acc[4] = {0.f, 0.f, 0.f, 0.f};

    int e = e0;
    while (e < e1) {
        int cnt = e1 - e;
        if (cnt > CH) cnt = CH;
        // ---- score phase: one (edge,head) per lane ----
        float w = 0.f;
        int s = 0;
        if (js < cnt) {
            s = csr_src[e + js];
            float xx = fminf(leakyf(el[(size_t)s * H + hs] + er_s), 80.f);
            w = __expf(xx);
        }
        lw[wv][lane] = w;                       // H==4: idx = js*4+hs == lane
        if (H == 4) { if (hs == 0) ls[wv][js] = s; }
        else ls[wv][lane] = s;
        asm volatile("s_waitcnt lgkmcnt(0)" ::: "memory");  // wave-private LDS handoff

        // ---- aggregate phase: gather + FMA only ----
        int j = 0;
        for (; j + 2 <= cnt; j += 2) {
            float w0 = lw[wv][(H == 4) ? (j * 4 + hf) : j];
            float w1 = lw[wv][(H == 4) ? ((j + 1) * 4 + hf) : (j + 1)];
            int s0 = ls[wv][j], s1 = ls[wv][j + 1];
            den += w0 + w1;
            if (H == 4) {
                uint2 u0 = *(const uint2*)(fp + (size_t)s0 * D + lane * 4);
                uint2 u1 = *(const uint2*)(fp + (size_t)s1 * D + lane * 4);
                acc[0] += w0 * bflo(u0.x) + w1 * bflo(u1.x);
                acc[1] += w0 * bfhi(u0.x) + w1 * bfhi(u1.x);
                acc[2] += w0 * bflo(u0.y) + w1 * bflo(u1.y);
                acc[3] += w0 * bfhi(u0.y) + w1 * bfhi(u1.y);
            } else {
                acc[0] += w0 * bflo((unsigned)fp[(size_t)s0 * D + lane])
                        + w1 * bflo((unsigned)fp[(size_t)s1 * D + lane]);
            }
        }
        if (j < cnt) {
            float w0 = lw[wv][(H == 4) ? (j * 4 + hf) : j];
            int s0 = ls[wv][j];
            den += w0;
            if (H == 4) {
                uint2 u0 = *(const uint2*)(fp + (size_t)s0 * D + lane * 4);
                acc[0] += w0 * bflo(u0.x);
                acc[1] += w0 * bfhi(u0.x);
                acc[2] += w0 * bflo(u0.y);
                acc[3] += w0 * bfhi(u0.y);
            } else {
                acc[0] += w0 * bflo((unsigned)fp[(size_t)s0 * D + lane]);
            }
        }
        e += cnt;
    }

    float inv = den > 0.f ? 1.f / den : 0.f;
    float v[4];
#pragma unroll
    for (int i = 0; i < 4; ++i) v[i] = acc[i] * inv;

    if (RES == 1) {
        uint2 ru = *(const uint2*)((const unsigned short*)resid + (size_t)node * D + lane * 4);
        v[0] += bflo(ru.x); v[1] += bfhi(ru.x); v[2] += bflo(ru.y); v[3] += bfhi(ru.y);
    } else if (RES == 2) {
        v[0] += ((const float*)resid)[(size_t)node * D + lane];
    }
    if (ACT == 1) {
#pragma unroll
        for (int i = 0; i < 4; ++i) v[i] = v[i] > 0.f ? v[i] : __expf(v[i]) - 1.f;
    }
    if (OUT_BF16) {
        if (H == 4) {
            us4 o = {f2bf(v[0]), f2bf(v[1]), f2bf(v[2]), f2bf(v[3])};
            *(us4*)((unsigned short*)outv + (size_t)node * D + lane * 4) = o;
        } else {
            ((unsigned short*)outv)[(size_t)node * D + lane] = f2bf(v[0]);
        }
    } else {
        if (H == 4) {
            float4 o = {v[0], v[1], v[2], v[3]};
            *(float4*)((float*)outv + (size_t)node * D + lane * 4) = o;
        } else {
            ((float*)outv)[(size_t)node * D + lane] = v[0];
        }
    }
}

// ---------------- launcher ----------------------------------------------------------------
extern "C" void kernel_launch(void* const* d_in, const int* in_sizes, int n_in,
                              void* d_out, int out_size, void* d_ws, size_t ws_size,
                              hipStream_t stream) {
    const float* x      = (const float*)d_in[0];
    const float* W1     = (const float*)d_in[1];
    const float* al1    = (const float*)d_in[2];
    const float* ar1    = (const float*)d_in[3];
    const float* W2     = (const float*)d_in[4];
    const float* al2    = (const float*)d_in[5];
    const float* ar2    = (const float*)d_in[6];
    const float* W3     = (const float*)d_in[7];
    const float* al3    = (const float*)d_in[8];
    const float* ar3    = (const float*)d_in[9];
    const float* res_W3 = (const float*)d_in[10];
    const int*   src    = (const int*)d_in[11];
    const int*   dst    = (const int*)d_in[12];

    const int N = in_sizes[0] / 128;    // 50000
    const int E = in_sizes[11];         // 500000

    float* out = (float*)d_out;

    // workspace layout
    unsigned short* featb = (unsigned short*)d_ws;          // [N,256] (layer3: [N,64])
    unsigned short* h1    = featb + (size_t)N * 256;        // [N,256]
    unsigned short* h2    = h1 + (size_t)N * 256;           // [N,256]
    unsigned short* W1t   = h2 + (size_t)N * 256;           // [256,128]
    unsigned short* W2t   = W1t + 256 * 128;                // [256,256]
    unsigned short* W3c   = W2t + 256 * 256;                // [128,256] = [W3t | RW3t]
    float* resf = (float*)(W3c + 128 * 256);                // [N,64]
    float* el   = resf + (size_t)N * 64;                    // [N,4]
    float* er   = el + (size_t)N * 4;                       // [N,4]
    int* offsets = (int*)(er + (size_t)N * 4);              // [N+1]
    int* cursor  = offsets + (N + 1);                       // [N]
    int* csr_src = cursor + N;                              // [E]
    int* bsums   = csr_src + E;                             // [64]

    const int T = 256;
    const int scan_blocks = (N + 1023) / 1024;  // 49 (must be <= 64 for add_off)

    // ---- weight conversions (fused) ----
    tconv_all<<<512, T, 0, stream>>>(W1, W2, W3, res_W3, W1t, W2t, W3c);

    // ---- CSR by dst ----
    hipMemsetAsync(cursor, 0, (size_t)N * sizeof(int), stream);
    hist_kernel<<<(E + T - 1) / T, T, 0, stream>>>(dst, cursor, E);
    scan_block<<<scan_blocks, 1024, 0, stream>>>(cursor, offsets, bsums, N);
    add_off<<<scan_blocks, 1024, 0, stream>>>(bsums, offsets, cursor, N, E, scan_blocks);
    scatter_kernel<<<(E + T - 1) / T, T, 0, stream>>>(src, dst, cursor, csr_src, E);

    int gemm12_blocks = (N + 63) / 64;
    int gemm3_blocks = (N + 127) / 128;
    int node_blocks = (N + 3) / 4;

    // ---- Layer 1: feat = x(f32) @ W1 (+el/er) ; agg -> h1 (elu, bf16) ----
    gemm_l12<true><<<gemm12_blocks, T, 0, stream>>>(x, W1t, featb, al1, ar1, el, er, N, 128);
    gat_agg<4, 0, 1, true><<<node_blocks, T, 0, stream>>>(featb, el, er, offsets, csr_src, nullptr, h1, N);

    // ---- Layer 2: feat = h1 @ W2 (+el/er) ; agg + resid(h1) -> h2 (elu, bf16) ----
    gemm_l12<false><<<gemm12_blocks, T, 0, stream>>>(h1, W2t, featb, al2, ar2, el, er, N, 256);
    gat_agg<4, 1, 1, true><<<node_blocks, T, 0, stream>>>(featb, el, er, offsets, csr_src, h1, h2, N);

    // ---- Layer 3: [feat|res] = h2 @ [W3|res_W3] (+el/er) ; agg + res -> out (f32) ----
    gemm_l3<<<gemm3_blocks, T, 0, stream>>>(h2, W3c, featb, resf, al3, ar3, el, er, N);
    gat_agg<1, 2, 0, false><<<node_blocks, T, 0, stream>>>(featb, el, er, offsets, csr_src, resf, out, N);
}